// Round 4
// baseline (52.032 us; speedup 1.0000x reference)
//
#include <hip/hip_runtime.h>

#define B     512
#define NBG   10000
#define F     32
#define H     128
#define CHUNK 20
#define NBLK  500     // NBLK*CHUNK == NBG
#define RB    8       // batch rows per prep block

// ---------------- Kernel A: MLP, 8 rows per block -> XT[f][b], babsT[f][b] ----------------
__global__ __launch_bounds__(128) void prep_kernel(
    const float* __restrict__ X,
    const float* __restrict__ W0, const float* __restrict__ b0,
    const float* __restrict__ W1, const float* __restrict__ b1,
    const float* __restrict__ Wout, const float* __restrict__ bout,
    float* __restrict__ XT,
    float* __restrict__ babsT)
{
    __shared__ __align__(16) float xr[RB][F];
    __shared__ __align__(16) float h0[RB][H];
    __shared__ __align__(16) float h1[RB][H];

    const int t  = threadIdx.x;
    const int r0 = blockIdx.x * RB;

    for (int i = t; i < RB * F; i += 128) {
        int r = i >> 5, f = i & 31;
        float xv = X[(r0 + r) * F + f];
        xr[r][f] = xv;
        XT[f * B + r0 + r] = xv;
    }
    __syncthreads();

    // layer 0: thread t = neuron t, RB rows at once
    float acc[RB];
    #pragma unroll
    for (int r = 0; r < RB; ++r) acc[r] = b0[t];
    #pragma unroll
    for (int f4 = 0; f4 < F / 4; ++f4) {
        float wa = W0[(4*f4+0)*H + t];
        float wb = W0[(4*f4+1)*H + t];
        float wc = W0[(4*f4+2)*H + t];
        float wd = W0[(4*f4+3)*H + t];
        #pragma unroll
        for (int r = 0; r < RB; ++r) {
            float4 xv = *(const float4*)&xr[r][4*f4];
            acc[r] += xv.x*wa + xv.y*wb + xv.z*wc + xv.w*wd;
        }
    }
    #pragma unroll
    for (int r = 0; r < RB; ++r) h0[r][t] = fmaxf(acc[r], 0.f);
    __syncthreads();

    // layer 1
    #pragma unroll
    for (int r = 0; r < RB; ++r) acc[r] = b1[t];
    for (int j4 = 0; j4 < H / 4; ++j4) {
        float wa = W1[(4*j4+0)*H + t];
        float wb = W1[(4*j4+1)*H + t];
        float wc = W1[(4*j4+2)*H + t];
        float wd = W1[(4*j4+3)*H + t];
        #pragma unroll
        for (int r = 0; r < RB; ++r) {
            float4 hv = *(const float4*)&h0[r][4*j4];
            acc[r] += hv.x*wa + hv.y*wb + hv.z*wc + hv.w*wd;
        }
    }
    #pragma unroll
    for (int r = 0; r < RB; ++r) h1[r][t] = fmaxf(acc[r], 0.f);
    __syncthreads();

    // head: i = r*32 + f over RB*F = 256, two passes
    for (int i = t; i < RB * F; i += 128) {
        int r = i >> 5, f = i & 31;
        float a = bout[f];
        #pragma unroll
        for (int j4 = 0; j4 < H / 4; ++j4) {
            float4 hv = *(const float4*)&h1[r][4*j4];
            a += hv.x*Wout[(4*j4+0)*F + f] + hv.y*Wout[(4*j4+1)*F + f]
               + hv.z*Wout[(4*j4+2)*F + f] + hv.w*Wout[(4*j4+3)*F + f];
        }
        babsT[f * B + r0 + r] = fabsf(a);
    }
}

// ---------------- Kernel B: NW partial sums ----------------
// Thread = batch row b (512 = whole batch). Grid.x = background chunk.
// xq/bv per-lane in VGPRs (launch_bounds(512,4) -> 128-VGPR budget, no spill);
// point features wave-uniform -> s_load SGPR broadcast, inner op = 2 VALU/(f,n).
__global__ __launch_bounds__(512, 4) void nw_partial(
    const float* __restrict__ XT,
    const float* __restrict__ babsT,
    const float* __restrict__ xbg,
    const float* __restrict__ ybg,
    float* __restrict__ psw,
    float* __restrict__ pswy)
{
    const int b  = threadIdx.x;
    const int n0 = blockIdx.x * CHUNK;

    float xq[F], bv[F];
    #pragma unroll
    for (int f = 0; f < F; ++f) {
        xq[f] = XT[f * B + b];       // coalesced 256B/wave
        bv[f] = babsT[f * B + b];
    }
    #pragma unroll
    for (int f = 0; f < F; ++f)
        asm volatile("" : "+v"(xq[f]), "+v"(bv[f]));   // pin in VGPRs

    float sw = 0.f, swy = 0.f;

    #pragma unroll 2
    for (int n = n0; n < n0 + CHUNK; ++n) {
        const float* __restrict__ p = xbg + n * F;    // uniform -> s_load
        float d = 0.f;
        #pragma unroll
        for (int f = 0; f < F; ++f)
            d += bv[f] * fabsf(xq[f] - p[f]);
        const float w = __expf(-d);
        sw  += w;
        swy += w * ybg[n];
    }

    psw [blockIdx.x * B + b] = sw;    // coalesced
    pswy[blockIdx.x * B + b] = swy;
}

// ---------------- Kernel C: combine partials, normalize ----------------
__global__ __launch_bounds__(64) void nw_final(
    const float* __restrict__ psw,
    const float* __restrict__ pswy,
    float* __restrict__ out)
{
    const int b = blockIdx.x * 64 + threadIdx.x;
    float sw = 0.f, swy = 0.f;
    for (int c = 0; c < NBLK; ++c) {
        sw  += psw [c * B + b];       // coalesced across lanes
        swy += pswy[c * B + b];
    }
    out[b] = swy / sw;
}

extern "C" void kernel_launch(void* const* d_in, const int* in_sizes, int n_in,
                              void* d_out, int out_size, void* d_ws, size_t ws_size,
                              hipStream_t stream)
{
    const float* X    = (const float*)d_in[0];
    const float* xbg  = (const float*)d_in[1];
    const float* ybg  = (const float*)d_in[2];
    const float* W0   = (const float*)d_in[3];
    const float* b0   = (const float*)d_in[4];
    const float* W1   = (const float*)d_in[5];
    const float* b1   = (const float*)d_in[6];
    const float* Wout = (const float*)d_in[7];
    const float* bout = (const float*)d_in[8];
    float* out = (float*)d_out;

    float* XT    = (float*)d_ws;             // F*B floats
    float* babsT = XT + F * B;               // F*B floats
    float* psw   = babsT + F * B;            // NBLK*B floats (1 MB)
    float* pswy  = psw + NBLK * B;           // NBLK*B floats (1 MB)

    prep_kernel<<<B / RB, 128, 0, stream>>>(X, W0, b0, W1, b1, Wout, bout, XT, babsT);
    nw_partial<<<NBLK, B, 0, stream>>>(XT, babsT, xbg, ybg, psw, pswy);
    nw_final<<<B / 64, 64, 0, stream>>>(psw, pswy, out);
}

// Round 5
// 43.199 us; speedup vs baseline: 1.2045x; 1.2045x over previous
//
#include <hip/hip_runtime.h>

#define B     512
#define NBG   10000
#define F     32
#define H     128
#define CHUNK 20
#define NBLK  500      // NBLK*CHUNK == NBG exactly
#define NP    10240    // padded row length for xbgT (pads never read)
#define RB    8        // batch rows per MLP block
#define MLPBLK (B / RB)     // 64
#define TRBLK  (NP / 128)   // 80

// ---------------- Kernel A: MLP (blocks 0..63) + xbg transpose (blocks 64..143) ----------------
__global__ __launch_bounds__(128) void prep_kernel(
    const float* __restrict__ X,
    const float* __restrict__ xbg,
    const float* __restrict__ W0, const float* __restrict__ b0,
    const float* __restrict__ W1, const float* __restrict__ b1,
    const float* __restrict__ Wout, const float* __restrict__ bout,
    float* __restrict__ XT,
    float* __restrict__ babsT,
    float* __restrict__ xbgT)
{
    __shared__ __align__(16) float lds[128 * 33];   // 16.9 KB, shared by both branches
    const int t = threadIdx.x;

    if (blockIdx.x < MLPBLK) {
        // ---- MLP for rows r0..r0+7 -> XT[f][b], babsT[f][b] ----
        const int r0 = blockIdx.x * RB;
        float* xr = lds;                 // [RB][F]   256
        float* h0 = lds + RB * F;        // [RB][H]   1024
        float* h1 = lds + RB * (F + H);  // [RB][H]   1024

        for (int i = t; i < RB * F; i += 128) {
            int r = i >> 5, f = i & 31;
            float xv = X[(r0 + r) * F + f];
            xr[r * F + f] = xv;
            XT[f * B + r0 + r] = xv;
        }
        __syncthreads();

        float acc[RB];
        #pragma unroll
        for (int r = 0; r < RB; ++r) acc[r] = b0[t];
        #pragma unroll
        for (int f4 = 0; f4 < F / 4; ++f4) {
            float wa = W0[(4*f4+0)*H + t];
            float wb = W0[(4*f4+1)*H + t];
            float wc = W0[(4*f4+2)*H + t];
            float wd = W0[(4*f4+3)*H + t];
            #pragma unroll
            for (int r = 0; r < RB; ++r) {
                float4 xv = *(const float4*)&xr[r * F + 4*f4];
                acc[r] += xv.x*wa + xv.y*wb + xv.z*wc + xv.w*wd;
            }
        }
        #pragma unroll
        for (int r = 0; r < RB; ++r) h0[r * H + t] = fmaxf(acc[r], 0.f);
        __syncthreads();

        #pragma unroll
        for (int r = 0; r < RB; ++r) acc[r] = b1[t];
        for (int j4 = 0; j4 < H / 4; ++j4) {
            float wa = W1[(4*j4+0)*H + t];
            float wb = W1[(4*j4+1)*H + t];
            float wc = W1[(4*j4+2)*H + t];
            float wd = W1[(4*j4+3)*H + t];
            #pragma unroll
            for (int r = 0; r < RB; ++r) {
                float4 hv = *(const float4*)&h0[r * H + 4*j4];
                acc[r] += hv.x*wa + hv.y*wb + hv.z*wc + hv.w*wd;
            }
        }
        #pragma unroll
        for (int r = 0; r < RB; ++r) h1[r * H + t] = fmaxf(acc[r], 0.f);
        __syncthreads();

        for (int i = t; i < RB * F; i += 128) {
            int r = i >> 5, f = i & 31;
            float a = bout[f];
            #pragma unroll
            for (int j4 = 0; j4 < H / 4; ++j4) {
                float4 hv = *(const float4*)&h1[r * H + 4*j4];
                a += hv.x*Wout[(4*j4+0)*F + f] + hv.y*Wout[(4*j4+1)*F + f]
                   + hv.z*Wout[(4*j4+2)*F + f] + hv.w*Wout[(4*j4+3)*F + f];
            }
            babsT[f * B + r0 + r] = fabsf(a);
        }
    } else {
        // ---- transpose 128 points into xbgT[f][n] (pads never read) ----
        const int nb = (blockIdx.x - MLPBLK) * 128;

        #pragma unroll
        for (int k = 0; k < 32; ++k) {
            int idx = k * 128 + t;          // coalesced over global floats
            int nl  = idx >> 5;
            int f   = idx & 31;
            int n   = nb + nl;
            lds[nl * 33 + f] = (n < NBG) ? xbg[n * F + f] : 0.f;
        }
        __syncthreads();

        #pragma unroll
        for (int f = 0; f < F; ++f)
            xbgT[f * NP + nb + t] = lds[t * 33 + f];   // coalesced 512B stores
    }
}

// ---------------- Kernel B: NW partial sums, f-outer / point-tile-inner ----------------
// Thread = batch row b. Block = one chunk of CHUNK=20 background points.
// d[20] statically indexed -> registers (~45 VGPR, nothing to spill).
// Per f: 2 coalesced per-lane loads + one uniform 80B s_load (SGPR broadcast);
// inner op = v_sub + v_fma(abs) : 2 VALU per (f,n).
__global__ __launch_bounds__(512) void nw_partial(
    const float* __restrict__ XT,
    const float* __restrict__ babsT,
    const float* __restrict__ xbgT,
    const float* __restrict__ ybg,
    float* __restrict__ psw,
    float* __restrict__ pswy)
{
    const int b  = threadIdx.x;
    const int n0 = blockIdx.x * CHUNK;

    float d[CHUNK];
    #pragma unroll
    for (int j = 0; j < CHUNK; ++j) d[j] = 0.f;

    #pragma unroll 2
    for (int f = 0; f < F; ++f) {
        const float xqf = XT[f * B + b];          // coalesced, L1-resident
        const float bvf = babsT[f * B + b];
        const float* __restrict__ p = xbgT + f * NP + n0;   // uniform -> s_load
        #pragma unroll
        for (int j = 0; j < CHUNK; ++j)
            d[j] += bvf * fabsf(xqf - p[j]);
    }

    float sw = 0.f, swy = 0.f;
    const float* __restrict__ y = ybg + n0;       // uniform -> s_load
    #pragma unroll
    for (int j = 0; j < CHUNK; ++j) {
        float w = __expf(-d[j]);
        sw  += w;
        swy += w * y[j];
    }

    psw [blockIdx.x * B + b] = sw;    // coalesced
    pswy[blockIdx.x * B + b] = swy;
}

// ---------------- Kernel C: combine partials, normalize ----------------
// One block per batch row; 64 lanes stride the 500 chunks; shfl reduce.
__global__ __launch_bounds__(64) void nw_final(
    const float* __restrict__ psw,
    const float* __restrict__ pswy,
    float* __restrict__ out)
{
    const int b = blockIdx.x;
    const int t = threadIdx.x;

    float sw = 0.f, swy = 0.f;
    for (int c = t; c < NBLK; c += 64) {
        sw  += psw [c * B + b];
        swy += pswy[c * B + b];
    }
    #pragma unroll
    for (int off = 32; off > 0; off >>= 1) {
        sw  += __shfl_down(sw,  off);
        swy += __shfl_down(swy, off);
    }
    if (t == 0) out[b] = swy / sw;
}

extern "C" void kernel_launch(void* const* d_in, const int* in_sizes, int n_in,
                              void* d_out, int out_size, void* d_ws, size_t ws_size,
                              hipStream_t stream)
{
    const float* X    = (const float*)d_in[0];
    const float* xbg  = (const float*)d_in[1];
    const float* ybg  = (const float*)d_in[2];
    const float* W0   = (const float*)d_in[3];
    const float* b0   = (const float*)d_in[4];
    const float* W1   = (const float*)d_in[5];
    const float* b1   = (const float*)d_in[6];
    const float* Wout = (const float*)d_in[7];
    const float* bout = (const float*)d_in[8];
    float* out = (float*)d_out;

    float* XT    = (float*)d_ws;              // F*B
    float* babsT = XT + F * B;                // F*B
    float* xbgT  = babsT + F * B;             // F*NP  (1.31 MB)
    float* psw   = xbgT + F * NP;             // NBLK*B (1 MB)
    float* pswy  = psw + NBLK * B;            // NBLK*B (1 MB)

    prep_kernel<<<MLPBLK + TRBLK, 128, 0, stream>>>(X, xbg, W0, b0, W1, b1,
                                                    Wout, bout, XT, babsT, xbgT);
    nw_partial<<<NBLK, B, 0, stream>>>(XT, babsT, xbgT, ybg, psw, pswy);
    nw_final<<<B, 64, 0, stream>>>(psw, pswy, out);
}